// Round 2
// baseline (775.184 us; speedup 1.0000x reference)
//
#include <hip/hip_runtime.h>
#include <hip/hip_bf16.h>

#define FDIM 15
#define HDIM 128
#define LNUM 12
#define NBINS 16
#define MDIM 47
#define FM 705
#define BATCH 65536
#define TAILF 3.0f
#define MIN_Wc 0.001f
#define MIN_Hc 0.001f
#define MIN_Dc 0.001f

typedef __bf16 bf16_t;
typedef __attribute__((ext_vector_type(8))) __bf16 bf16x8;
typedef __attribute__((ext_vector_type(4))) __bf16 bf16x4;
typedef __attribute__((ext_vector_type(4))) float f32x4;

// sparse fragment schedule (degree-sorted hidden units):
//   init 8 | residual 4*23=92 | out 111  => 211 frags used.
// Padded to 216 per layer (multiple of RING=8): ring phase identical every
// layer; tail prefetches land on the next layer's frags (wfrag contiguous).
#define FRAGS_USED 211
#define FRAGS_PAD 216
#define FRAG_ELEMS 512            // 64 lanes * 8 bf16 = 1 KB
#define RING 8
#define WFRAG_TOTAL (LNUM * FRAGS_PAD * FRAG_ELEMS)

// bias blob per layer: bI(128) | bR(512) | bOpad(15*48=720) = 1360 floats
#define BB_FLOATS 1360
#define BB_TOTAL (LNUM * BB_FLOATS)

#define SPW 16                    // samples per wave (1 N-tile of 16)
#define RAW_ROWS 48               // 3 features x 16 samples per out-round
#define RAW_STRIDE 52             // odd # of 16B units -> conflict-free b128
#define RAW_BYTES (RAW_ROWS * RAW_STRIDE * 4)   // 9984; Bst (4352) unions here

// degree-sorted permutation: pos -> original hidden index.
__device__ __forceinline__ int perm_pos(int pos) {
    int r, o;
    if (pos < 20) { r = pos / 10; o = pos % 10; }
    else          { r = 2 + (pos - 20) / 9; o = (pos - 20) % 9; }
    return r + 14 * o;
}

__device__ __forceinline__ float sp_softplus(float u) {
    return (u > 20.f) ? u : __logf(1.f + __expf(u));
}

// ---------------- preproc: sparse-scheduled wfrag + permuted bias blob ----------------
__global__ void preproc_kernel(const float* __restrict__ Wi,
                               const float* __restrict__ Wr,
                               const float* __restrict__ Wo,
                               const float* __restrict__ bIg,
                               const float* __restrict__ bRg,
                               const float* __restrict__ bOg,
                               bf16_t* __restrict__ wfrag,
                               float* __restrict__ bblob) {
    const int RES_OFF[8] = {0, 1, 3, 5, 8, 11, 15, 19};
    const int OUT_OFF[15] = {0, 0, 3, 6, 9, 15, 21, 27, 36, 45, 54, 63, 75, 87, 99};
    const int OUT_CNT[15] = {0, 1, 1, 1, 2, 2, 2, 3, 3, 3, 3, 4, 4, 4, 4};

    int idx = blockIdx.x * blockDim.x + threadIdx.x;
    if (idx >= WFRAG_TOTAL) {
        int t = idx - WFRAG_TOTAL;
        if (t >= BB_TOTAL) return;
        int l = t / BB_FLOATS, r = t % BB_FLOATS;
        float v;
        if (r < 128) v = bIg[l * HDIM + perm_pos(r)];
        else if (r < 640) {
            int mat = (r - 128) >> 7, pos = (r - 128) & 127;
            v = bRg[(l * 4 + mat) * HDIM + perm_pos(pos)];
        } else {
            int q = r - 640, f = q / 48, j = q % 48;
            v = (j < 47) ? bOg[(size_t)l * FM + f * MDIM + j] : 0.f;
        }
        bblob[t] = v;
        return;
    }
    int j = idx & 7;
    int lane = (idx >> 3) & 63;
    int fg = idx >> 9;
    int g = fg % FRAGS_PAD;
    int l = fg / FRAGS_PAD;
    int quad = lane >> 4, n16 = lane & 15;
    int kk = quad * 8 + j;
    float val = 0.f;
    if (g < 8) {
        int n_orig = perm_pos(g * 16 + n16);
        if (kk < FDIM && (n_orig % 14) >= kk)
            val = Wi[(l * HDIM + n_orig) * FDIM + kk];
    } else if (g < 100) {
        int gg = g - 8;
        int mat = gg / 23, r = gg % 23;
        int mt = 7;
        while (mt > 0 && RES_OFF[mt] > r) mt--;
        int s = r - RES_OFF[mt];
        int j_orig = perm_pos(mt * 16 + n16);
        int k_orig = perm_pos(s * 32 + kk);
        if ((j_orig % 14) >= (k_orig % 14))
            val = Wr[((size_t)(l * 4 + mat) * HDIM + j_orig) * HDIM + k_orig];
    } else if (g < 211) {
        int gg = g - 100;
        int f = 14;
        while (f > 1 && OUT_OFF[f] > gg) f--;
        int q = gg - OUT_OFF[f];
        int cnt = OUT_CNT[f];
        int ty = q / cnt, s = q % cnt;
        int k_orig = perm_pos(s * 32 + kk);
        int o = (ty < 2) ? (f * MDIM + ty * 16 + n16)
                         : ((n16 < 15) ? (f * MDIM + 32 + n16) : -1);
        if (o >= 0 && f > (k_orig % 14))
            val = Wo[((size_t)l * FM + o) * HDIM + k_orig];
    }
    // g in [211,216): zero pad
    wfrag[idx] = (bf16_t)val;
}

// ---------------- fused 12-layer flow kernel ----------------
// One wave per block (64 threads), 16 samples/wave: 4096 independent waves
// (3.5 waves/SIMD, LDS-limited). ZERO barriers. Weights stream global->VGPR
// through an 8-deep register ring (L2 latency hidden by TLP, not ring depth).
__global__ __launch_bounds__(64, 4) void flow_kernel(
    const float* __restrict__ xin,
    float* __restrict__ zout,
    float* __restrict__ ldout,
    const bf16_t* __restrict__ wfrag,
    const float* __restrict__ bblob) {

    constexpr int RES_CNT_C[8] = {1, 2, 2, 3, 3, 4, 4, 4};
    constexpr int OUT_CNT_C[15] = {0, 1, 1, 1, 2, 2, 2, 3, 3, 3, 3, 4, 4, 4, 4};

    __shared__ __align__(16) float xs[SPW * 17];            // 1088 B
    __shared__ __align__(16) unsigned char uni[RAW_BYTES];  // 9984 B: Bst[16][136]bf16 U raw[48][52]f32

    const int ln = threadIdx.x;                 // 0..63
    const int quad = ln >> 4, n16 = ln & 15;
    const int fi = ln & 3, srow = ln >> 2;      // spline: feature-in-round / sample
    const int sbase = blockIdx.x * SPW;

    bf16_t* Bst = (bf16_t*)uni;
    float*  raw = (float*)uni;

    // load x (16 samples x 15), coalesced
    for (int t = ln; t < SPW * FDIM; t += 64) {
        int s = t / FDIM, c = t % FDIM;
        xs[s * 17 + c] = xin[(size_t)sbase * FDIM + t];
    }

    // ---- weight ring prologue: frags 0..7 of layer 0 in flight
    const bf16_t* wl = wfrag;
    bf16x8 Q[RING];
#pragma unroll
    for (int j = 0; j < RING; j++)
        Q[j] = *((const bf16x8*)(wl + (size_t)j * FRAG_ELEMS) + ln);

    float lad_sum = 0.f;
    bf16x8 bf[4];        // staged act B-frags (k-tiles in sorted hidden space)
    f32x4 h[8];          // persistent carry: rows = hidden (sorted), col = sample n16

#pragma unroll 1
    for (int l = 0; l < LNUM; l++) {
        const float* bias = bblob + l * BB_FLOATS;

        // spline x-inputs (reversed frame), snapshot BEFORE any spline write
        float xc_pre[5];
#pragma unroll
        for (int p = 0; p < 5; p++) {
            int f = 3 * p + fi;
            xc_pre[p] = xs[srow * 17 + ((f < FDIM) ? (14 - f) : 0)];
        }
        // init-GEMM act B fragment from reversed xs, K padded 15->32
        bf16x8 a0;
#pragma unroll
        for (int j = 0; j < 8; j++) {
            int k = quad * 8 + j;
            a0[j] = (bf16_t)((k < FDIM) ? xs[n16 * 17 + 14 - k] : 0.f);
        }

        // ---- per-layer frag consumption with ring refill (no barriers)
        int fp = 0;
        auto ldfrag = [&]() -> bf16x8 {
            bf16x8 r = Q[fp & (RING - 1)];
            Q[fp & (RING - 1)] =
                *((const bf16x8*)(wl + (size_t)(fp + RING) * FRAG_ELEMS) + ln);
            fp++;
            return r;
        };

        auto packmt = [&](int mt, f32x4 c, bool relu) {
            bf16x4 pk;
#pragma unroll
            for (int r2 = 0; r2 < 4; r2++) {
                float v = c[r2];
                if (relu) v = fmaxf(v, 0.f);
                pk[r2] = (bf16_t)v;
            }
            *(bf16x4*)&Bst[n16 * 136 + mt * 16 + quad * 4] = pk;
        };
        auto readbf = [&]() {
#pragma unroll
            for (int s = 0; s < 4; s++)
                bf[s] = *(const bf16x8*)&Bst[n16 * 136 + s * 32 + quad * 8];
        };

        // ---- init GEMM (frags 0..7), pack relu(h)
#pragma unroll
        for (int mt = 0; mt < 8; mt++) {
            f32x4 bbv = *(const f32x4*)&bias[mt * 16 + quad * 4];
            bf16x8 wf = ldfrag();
            f32x4 c = __builtin_amdgcn_mfma_f32_16x16x32_bf16(wf, a0, bbv, 0, 0, 0);
            h[mt] = c;
            packmt(mt, c, true);
        }
        readbf();

        // ---- residual GEMMs fused with pack (frags 8..99)
        auto gemm_pack = [&](const float* bm, bool addto, bool relu) {
#pragma unroll
            for (int mt = 0; mt < 8; mt++) {
                f32x4 bbv = *(const f32x4*)&bm[mt * 16 + quad * 4];
                f32x4 acc = addto ? (h[mt] + bbv) : bbv;
#pragma unroll
                for (int s = 0; s < RES_CNT_C[mt]; s++) {
                    bf16x8 wf = ldfrag();
                    acc = __builtin_amdgcn_mfma_f32_16x16x32_bf16(wf, bf[s], acc, 0, 0, 0);
                }
                if (addto) h[mt] = acc;
                packmt(mt, acc, relu);
            }
            readbf();
        };

        gemm_pack(bias + 128 + 0 * HDIM, false, true);   // t = W1a . relu(h)
        gemm_pack(bias + 128 + 1 * HDIM, true,  true);   // h += W1b . relu(t)
        gemm_pack(bias + 128 + 2 * HDIM, false, true);   // t = W2a . relu(h)
        gemm_pack(bias + 128 + 3 * HDIM, true,  false);  // h += W2b . relu(t); pack h

        // ---- out GEMM (frags 100..210) in 5 rounds of 3 features + spline
        const float* bO48 = bias + 640;

#pragma unroll
        for (int p = 0; p < 5; p++) {
#pragma unroll
            for (int ff = 0; ff < 3; ff++) {
                const int f = 3 * p + ff;
                const int cnt = OUT_CNT_C[f];
#pragma unroll
                for (int ty = 0; ty < 3; ty++) {
                    f32x4 acc = *(const f32x4*)&bO48[f * 48 + ty * 16 + quad * 4];
#pragma unroll
                    for (int s = 0; s < cnt; s++) {
                        bf16x8 wf = ldfrag();
                        acc = __builtin_amdgcn_mfma_f32_16x16x32_bf16(wf, bf[s], acc, 0, 0, 0);
                    }
                    *(f32x4*)&raw[(ff * 16 + n16) * RAW_STRIDE + ty * 16 + quad * 4] = acc;
                }
            }

            // spline: lanes fi<3 handle (sample srow, feature 3p+fi)
            if (fi < 3) {
                int f = 3 * p + fi;
                const float* rp = &raw[(fi * 16 + srow) * RAW_STRIDE];
                float xr = xc_pre[p];
                bool inside = (xr >= -TAILF) && (xr <= TAILF);
                float xcv = fminf(fmaxf(xr, -TAILF), TAILF);

                // ALL raw reads upfront (uw, uh, d) -> next round's raw writes
                // only wait on these early reads, not on the scan.
                float uw[NBINS], uh[NBINS], dval[NBINS];
                {
                    f32x4 v0 = *(const f32x4*)(rp + 0);
                    f32x4 v1 = *(const f32x4*)(rp + 4);
                    f32x4 v2 = *(const f32x4*)(rp + 8);
                    f32x4 v3 = *(const f32x4*)(rp + 12);
                    f32x4 w0 = *(const f32x4*)(rp + 16);
                    f32x4 w1 = *(const f32x4*)(rp + 20);
                    f32x4 w2 = *(const f32x4*)(rp + 24);
                    f32x4 w3 = *(const f32x4*)(rp + 28);
                    f32x4 d0v = *(const f32x4*)(rp + 32);
                    f32x4 d1v = *(const f32x4*)(rp + 36);
                    f32x4 d2v = *(const f32x4*)(rp + 40);
                    f32x4 d3v = *(const f32x4*)(rp + 44);
#pragma unroll
                    for (int i = 0; i < 4; i++) {
                        uw[i] = v0[i]; uw[4 + i] = v1[i]; uw[8 + i] = v2[i]; uw[12 + i] = v3[i];
                        uh[i] = w0[i]; uh[4 + i] = w1[i]; uh[8 + i] = w2[i]; uh[12 + i] = w3[i];
                        dval[i] = d0v[i]; dval[4 + i] = d1v[i];
                        dval[8 + i] = d2v[i]; dval[12 + i] = d3v[i];
                    }
                }
                float mw = -1e30f, mh = -1e30f;
#pragma unroll
                for (int i = 0; i < NBINS; i++) {
                    mw = fmaxf(mw, uw[i]); mh = fmaxf(mh, uh[i]);
                }
                float swv = 0.f, shv = 0.f;
#pragma unroll
                for (int i = 0; i < NBINS; i++) {
                    uw[i] = __expf(uw[i] - mw); swv += uw[i];
                    uh[i] = __expf(uh[i] - mh); shv += uh[i];
                }
                float isw = (1.f - NBINS * MIN_Wc) * __builtin_amdgcn_rcpf(swv);
                float ish = (1.f - NBINS * MIN_Hc) * __builtin_amdgcn_rcpf(shv);

                float cumw = 0.f, cumh = 0.f;
                float left = -TAILF, chl_run = -TAILF;
                float lw = -TAILF, wsel = 1.f, chl = -TAILF, hsel = 1.f;
                float d0r = 0.f, d1r = 0.f;
                int idx = 0;
#pragma unroll
                for (int b = 0; b < NBINS; b++) {
                    float wb = MIN_Wc + uw[b] * isw;
                    float hb = MIN_Hc + uh[b] * ish;
                    cumw += wb; cumh += hb;
                    float cwr = (b == NBINS - 1) ? TAILF : 2.f * TAILF * cumw - TAILF;
                    float chr = (b == NBINS - 1) ? TAILF : 2.f * TAILF * cumh - TAILF;
                    bool inb = (xcv >= left) && ((xcv < cwr) || (b == NBINS - 1));
                    if (inb) {
                        idx = b; lw = left; wsel = cwr - left;
                        chl = chl_run; hsel = chr - chl_run;
                        d0r = (b > 0) ? dval[b - 1] : 0.f;
                        d1r = (b < NBINS - 1) ? dval[b] : 0.f;
                    }
                    left = cwr; chl_run = chr;
                }
                float d0 = (idx > 0) ? (MIN_Dc + sp_softplus(d0r)) : 1.f;
                float d1 = (idx < NBINS - 1) ? (MIN_Dc + sp_softplus(d1r)) : 1.f;

                float rw = __builtin_amdgcn_rcpf(wsel);
                float delta = hsel * rw;
                float th = (xcv - lw) * rw;
                float omt = 1.f - th;
                float tomt = th * omt;
                float num = hsel * (delta * th * th + d0 * tomt);
                float den = delta + (d0 + d1 - 2.f * delta) * tomt;
                float y = chl + num * __builtin_amdgcn_rcpf(den);
                float dnum = delta * delta * (d1 * th * th + 2.f * delta * tomt + d0 * omt * omt);
                float lad = __logf(dnum) - 2.f * __logf(den);

                y = inside ? y : xr;
                lad = inside ? lad : 0.f;
                xs[srow * 17 + f] = y;
                lad_sum += lad;
            }
        }

        // ---- advance ring over pad frags 211..215 (keeps ring phase across layers)
#pragma unroll
        for (int d = 0; d < FRAGS_PAD - FRAGS_USED; d++) {
            (void)ldfrag();
        }

        wl += (size_t)FRAGS_PAD * FRAG_ELEMS;
    }

    // ---- epilogue: logdet (4-lane group sum: fi=0..2 contribute) + z write
    float v = lad_sum;
    v += __shfl_xor(v, 1);
    v += __shfl_xor(v, 2);
    if (fi == 0) ldout[(size_t)sbase + srow] = v;

    for (int t = ln; t < SPW * FDIM; t += 64) {
        int s = t / FDIM, c = t % FDIM;
        zout[(size_t)sbase * FDIM + t] = xs[s * 17 + c];
    }
}

extern "C" void kernel_launch(void* const* d_in, const int* in_sizes, int n_in,
                              void* d_out, int out_size, void* d_ws, size_t ws_size,
                              hipStream_t stream) {
    const float* x  = (const float*)d_in[0];
    const float* Wi = (const float*)d_in[1];
    const float* bI = (const float*)d_in[2];
    const float* Wr = (const float*)d_in[3];
    const float* bR = (const float*)d_in[4];
    const float* Wo = (const float*)d_in[5];
    const float* bO = (const float*)d_in[6];

    bf16_t* wfrag = (bf16_t*)d_ws;
    // slack of RING frags (8 KB) after the last layer for tail prefetches
    size_t woff = ((size_t)WFRAG_TOTAL * 2 + (size_t)RING * FRAG_ELEMS * 2 + 255) & ~(size_t)255;
    float* bblob = (float*)((char*)d_ws + woff);
    float* zout  = (float*)d_out;
    float* ldout_final = zout + (size_t)BATCH * FDIM;

    const int totalP = WFRAG_TOTAL + BB_TOTAL;
    preproc_kernel<<<(totalP + 255) / 256, 256, 0, stream>>>(Wi, Wr, Wo, bI, bR, bO, wfrag, bblob);

    flow_kernel<<<BATCH / SPW, 64, 0, stream>>>(x, zout, ldout_final, wfrag, bblob);
}

// Round 3
// 437.459 us; speedup vs baseline: 1.7720x; 1.7720x over previous
//
#include <hip/hip_runtime.h>
#include <hip/hip_bf16.h>

#define FDIM 15
#define HDIM 128
#define LNUM 12
#define NBINS 16
#define MDIM 47
#define FM 705
#define BATCH 65536
#define TAILF 3.0f
#define MIN_Wc 0.001f
#define MIN_Hc 0.001f
#define MIN_Dc 0.001f

typedef __bf16 bf16_t;
typedef __attribute__((ext_vector_type(8))) __bf16 bf16x8;
typedef __attribute__((ext_vector_type(4))) __bf16 bf16x4;
typedef __attribute__((ext_vector_type(2))) __bf16 bf16x2;
typedef __attribute__((ext_vector_type(4))) float f32x4;
typedef __attribute__((ext_vector_type(4))) int i32x4;

// sparse fragment schedule (degree-sorted hidden units):
//   init 8 | residual 4*23=92 | out 111  => 211 frags used.
// Padded to 224 per layer (multiple of RING=16): ring phase identical each
// layer; tail prefetches land on next layer's frags (wfrag contiguous).
#define FRAGS_USED 211
#define FRAGS_PAD 224
#define FRAG_ELEMS 512            // 64 lanes * 8 bf16 = 1 KB
#define RING 16
#define WFRAG_TOTAL (LNUM * FRAGS_PAD * FRAG_ELEMS)

// bias blob per layer: bI(128) | bR(512) | bOpad(15*48=720) = 1360 floats
#define BB_FLOATS 1360
#define BB_TOTAL (LNUM * BB_FLOATS)

#define SPW 32                    // samples per wave (2 N-tiles of 16)

// degree-sorted permutation: pos -> original hidden index.
__device__ __forceinline__ int perm_pos(int pos) {
    int r, o;
    if (pos < 20) { r = pos / 10; o = pos % 10; }
    else          { r = 2 + (pos - 20) / 9; o = (pos - 20) % 9; }
    return r + 14 * o;
}

__device__ __forceinline__ float sp_softplus(float u) {
    return (u > 20.f) ? u : __logf(1.f + __expf(u));
}

// ---------------- preproc: sparse-scheduled wfrag + permuted bias blob ----------------
__global__ void preproc_kernel(const float* __restrict__ Wi,
                               const float* __restrict__ Wr,
                               const float* __restrict__ Wo,
                               const float* __restrict__ bIg,
                               const float* __restrict__ bRg,
                               const float* __restrict__ bOg,
                               bf16_t* __restrict__ wfrag,
                               float* __restrict__ bblob) {
    const int RES_OFF[8] = {0, 1, 3, 5, 8, 11, 15, 19};
    const int OUT_OFF[15] = {0, 0, 3, 6, 9, 15, 21, 27, 36, 45, 54, 63, 75, 87, 99};
    const int OUT_CNT[15] = {0, 1, 1, 1, 2, 2, 2, 3, 3, 3, 3, 4, 4, 4, 4};

    int idx = blockIdx.x * blockDim.x + threadIdx.x;
    if (idx >= WFRAG_TOTAL) {
        int t = idx - WFRAG_TOTAL;
        if (t >= BB_TOTAL) return;
        int l = t / BB_FLOATS, r = t % BB_FLOATS;
        float v;
        if (r < 128) v = bIg[l * HDIM + perm_pos(r)];
        else if (r < 640) {
            int mat = (r - 128) >> 7, pos = (r - 128) & 127;
            v = bRg[(l * 4 + mat) * HDIM + perm_pos(pos)];
        } else {
            int q = r - 640, f = q / 48, j = q % 48;
            v = (j < 47) ? bOg[(size_t)l * FM + f * MDIM + j] : 0.f;
        }
        bblob[t] = v;
        return;
    }
    int j = idx & 7;
    int lane = (idx >> 3) & 63;
    int fg = idx >> 9;
    int g = fg % FRAGS_PAD;
    int l = fg / FRAGS_PAD;
    int quad = lane >> 4, n16 = lane & 15;
    int kk = quad * 8 + j;
    float val = 0.f;
    if (g < 8) {
        int n_orig = perm_pos(g * 16 + n16);
        if (kk < FDIM && (n_orig % 14) >= kk)
            val = Wi[(l * HDIM + n_orig) * FDIM + kk];
    } else if (g < 100) {
        int gg = g - 8;
        int mat = gg / 23, r = gg % 23;
        int mt = 7;
        while (mt > 0 && RES_OFF[mt] > r) mt--;
        int s = r - RES_OFF[mt];
        int j_orig = perm_pos(mt * 16 + n16);
        int k_orig = perm_pos(s * 32 + kk);
        if ((j_orig % 14) >= (k_orig % 14))
            val = Wr[((size_t)(l * 4 + mat) * HDIM + j_orig) * HDIM + k_orig];
    } else if (g < 211) {
        int gg = g - 100;
        int f = 14;
        while (f > 1 && OUT_OFF[f] > gg) f--;
        int q = gg - OUT_OFF[f];
        int cnt = OUT_CNT[f];
        int ty = q / cnt, s = q % cnt;
        int k_orig = perm_pos(s * 32 + kk);
        int o = (ty < 2) ? (f * MDIM + ty * 16 + n16)
                         : ((n16 < 15) ? (f * MDIM + 32 + n16) : -1);
        if (o >= 0 && f > (k_orig % 14))
            val = Wo[((size_t)l * FM + o) * HDIM + k_orig];
    }
    // g in [211,224): zero pad
    wfrag[idx] = (bf16_t)val;
}

// ---------------- fused 12-layer flow kernel ----------------
// One wave per block (64 threads), SPW=32. ZERO barriers, ZERO LDS traffic on
// the activation-repack path: the C-frag -> B-frag transpose is done in
// registers via ds_bpermute (fixed 64-lane permutation), so each GEMM phase's
// MFMAs can start as soon as the previous phase's first mt-pair is packed.
__global__ __launch_bounds__(64, 2) void flow_kernel(
    const float* __restrict__ xin,
    float* __restrict__ zout,
    float* __restrict__ ldout,
    const bf16_t* __restrict__ wfrag,
    const float* __restrict__ bblob) {

    constexpr int RES_CNT_C[8] = {1, 2, 2, 3, 3, 4, 4, 4};
    constexpr int OUT_CNT_C[15] = {0, 1, 1, 1, 2, 2, 2, 3, 3, 3, 3, 4, 4, 4, 4};

    __shared__ __align__(16) float xs[SPW * 17];     // 2176 B
    __shared__ __align__(16) float raw[64 * 52];     // 13312 B (out-round scratch)

    const int ln = threadIdx.x;                 // 0..63
    const int quad = ln >> 4, n16 = ln & 15;
    const int fi = ln & 1, srow = ln >> 1;
    const int sbase = blockIdx.x * SPW;

    // bpermute constants for the C->B transpose:
    // dst lane ln (qb=ln>>4, smp=ln&15) pulls j0..3 from src lane (qb&1)*32+smp
    // and j4..7 from that +16; mt parity selected by ln>=32.
    const int l0lane = ((ln >> 4) & 1) * 32 + (ln & 15);
    const int idx0 = l0lane << 2;
    const int idx1 = idx0 + 64;
    const bool hi = (ln >= 32);

    auto pack2 = [&](float a, float b, bool relu) -> int {
        if (relu) { a = fmaxf(a, 0.f); b = fmaxf(b, 0.f); }
        bf16x2 t; t[0] = (bf16_t)a; t[1] = (bf16_t)b;
        return __builtin_bit_cast(int, t);
    };
    // gather one B-frag (bf16x8) from even/odd mt packed dwords
    auto gath4 = [&](int e01, int e23, int o01, int o23) -> bf16x8 {
        int a0_ = __builtin_amdgcn_ds_bpermute(idx0, e01);
        int b0_ = __builtin_amdgcn_ds_bpermute(idx0, o01);
        int a1_ = __builtin_amdgcn_ds_bpermute(idx0, e23);
        int b1_ = __builtin_amdgcn_ds_bpermute(idx0, o23);
        int a2_ = __builtin_amdgcn_ds_bpermute(idx1, e01);
        int b2_ = __builtin_amdgcn_ds_bpermute(idx1, o01);
        int a3_ = __builtin_amdgcn_ds_bpermute(idx1, e23);
        int b3_ = __builtin_amdgcn_ds_bpermute(idx1, o23);
        i32x4 d;
        d[0] = hi ? b0_ : a0_;
        d[1] = hi ? b1_ : a1_;
        d[2] = hi ? b2_ : a2_;
        d[3] = hi ? b3_ : a3_;
        return __builtin_bit_cast(bf16x8, d);
    };

    // load x (32 samples x 15), coalesced
    for (int t = ln; t < SPW * FDIM; t += 64) {
        int s = t / FDIM, c = t % FDIM;
        xs[s * 17 + c] = xin[(size_t)sbase * FDIM + t];
    }

    // ---- weight ring prologue: frags 0..15 of layer 0 in flight
    const bf16_t* wl = wfrag;
    bf16x8 Q[RING];
#pragma unroll
    for (int j = 0; j < RING; j++)
        Q[j] = *((const bf16x8*)(wl + (size_t)j * FRAG_ELEMS) + ln);

    float lad_sum = 0.f;
    bf16x8 bf[2][4];      // staged act B-frags (k-tiles in sorted hidden space)
    bf16x8 bfn[2][4];     // next-phase B-frags being assembled
    f32x4 h[2][8];        // persistent carry: rows = hidden (sorted), col = sample n16

#pragma unroll 1
    for (int l = 0; l < LNUM; l++) {
        const float* bias = bblob + l * BB_FLOATS;

        // spline x-inputs (reversed frame), snapshot BEFORE any spline write
        float xc_pre[8];
#pragma unroll
        for (int p = 0; p < 8; p++) {
            int f = 2 * p + fi;
            xc_pre[p] = xs[srow * 17 + ((f < FDIM) ? (14 - f) : 0)];
        }
        // init-GEMM act B fragments from reversed xs, K padded 15->32
        bf16x8 a0[2];
#pragma unroll
        for (int T = 0; T < 2; T++)
#pragma unroll
            for (int j = 0; j < 8; j++) {
                int k = quad * 8 + j;
                a0[T][j] = (bf16_t)((k < FDIM) ? xs[(T * 16 + n16) * 17 + 14 - k] : 0.f);
            }

        // ---- per-layer frag consumption with ring refill (no barriers)
        int fp = 0;
        auto ldfrag = [&]() -> bf16x8 {
            bf16x8 r = Q[fp & (RING - 1)];
            Q[fp & (RING - 1)] =
                *((const bf16x8*)(wl + (size_t)(fp + RING) * FRAG_ELEMS) + ln);
            fp++;
            return r;
        };

        // ---- init GEMM (frags 0..7): h = Wi.x + b, pack relu via bpermute
        {
            int pe01_0, pe23_0, pe01_1, pe23_1;
#pragma unroll
            for (int mt = 0; mt < 8; mt++) {
                f32x4 bbv = *(const f32x4*)&bias[mt * 16 + quad * 4];
                bf16x8 wf = ldfrag();
                f32x4 c0 = __builtin_amdgcn_mfma_f32_16x16x32_bf16(wf, a0[0], bbv, 0, 0, 0);
                f32x4 c1 = __builtin_amdgcn_mfma_f32_16x16x32_bf16(wf, a0[1], bbv, 0, 0, 0);
                h[0][mt] = c0; h[1][mt] = c1;
                int p01_0 = pack2(c0[0], c0[1], true), p23_0 = pack2(c0[2], c0[3], true);
                int p01_1 = pack2(c1[0], c1[1], true), p23_1 = pack2(c1[2], c1[3], true);
                if (!(mt & 1)) { pe01_0 = p01_0; pe23_0 = p23_0; pe01_1 = p01_1; pe23_1 = p23_1; }
                else {
                    int s2 = mt >> 1;
                    bfn[0][s2] = gath4(pe01_0, pe23_0, p01_0, p23_0);
                    bfn[1][s2] = gath4(pe01_1, pe23_1, p01_1, p23_1);
                }
            }
#pragma unroll
            for (int T = 0; T < 2; T++)
#pragma unroll
                for (int s = 0; s < 4; s++) bf[T][s] = bfn[T][s];
        }

        // ---- residual GEMMs fused with in-register repack (frags 8..99)
        auto gemm_pack = [&](const float* bm, bool addto, bool relu) {
            int pe01_0, pe23_0, pe01_1, pe23_1;
#pragma unroll
            for (int mt = 0; mt < 8; mt++) {
                f32x4 bbv = *(const f32x4*)&bm[mt * 16 + quad * 4];
                f32x4 acc0 = addto ? (h[0][mt] + bbv) : bbv;
                f32x4 acc1 = addto ? (h[1][mt] + bbv) : bbv;
#pragma unroll
                for (int s = 0; s < RES_CNT_C[mt]; s++) {
                    bf16x8 wf = ldfrag();
                    acc0 = __builtin_amdgcn_mfma_f32_16x16x32_bf16(wf, bf[0][s], acc0, 0, 0, 0);
                    acc1 = __builtin_amdgcn_mfma_f32_16x16x32_bf16(wf, bf[1][s], acc1, 0, 0, 0);
                }
                if (addto) { h[0][mt] = acc0; h[1][mt] = acc1; }
                int p01_0 = pack2(acc0[0], acc0[1], relu), p23_0 = pack2(acc0[2], acc0[3], relu);
                int p01_1 = pack2(acc1[0], acc1[1], relu), p23_1 = pack2(acc1[2], acc1[3], relu);
                if (!(mt & 1)) { pe01_0 = p01_0; pe23_0 = p23_0; pe01_1 = p01_1; pe23_1 = p23_1; }
                else {
                    int s2 = mt >> 1;
                    bfn[0][s2] = gath4(pe01_0, pe23_0, p01_0, p23_0);
                    bfn[1][s2] = gath4(pe01_1, pe23_1, p01_1, p23_1);
                }
            }
#pragma unroll
            for (int T = 0; T < 2; T++)
#pragma unroll
                for (int s = 0; s < 4; s++) bf[T][s] = bfn[T][s];
        };

        gemm_pack(bias + 128 + 0 * HDIM, false, true);   // t = W1a . relu(h)
        gemm_pack(bias + 128 + 1 * HDIM, true,  true);   // h += W1b . relu(t)
        gemm_pack(bias + 128 + 2 * HDIM, false, true);   // t = W2a . relu(h)
        gemm_pack(bias + 128 + 3 * HDIM, true,  false);  // h += W2b . relu(t); pack h

        // ---- out GEMM (frags 100..210) in 2-feature rounds + spline
        const float* bO48 = bias + 640;

#pragma unroll
        for (int p = 0; p < 8; p++) {
            const int nf = (p < 7) ? 2 : 1;
#pragma unroll
            for (int ff = 0; ff < 2; ff++) {
                if (ff >= nf) break;
                const int f = 2 * p + ff;
                const int cnt = OUT_CNT_C[f];
#pragma unroll
                for (int ty = 0; ty < 3; ty++) {
                    f32x4 acc0 = *(const f32x4*)&bO48[f * 48 + ty * 16 + quad * 4];
                    f32x4 acc1 = acc0;
#pragma unroll
                    for (int s = 0; s < cnt; s++) {
                        bf16x8 wf = ldfrag();
                        acc0 = __builtin_amdgcn_mfma_f32_16x16x32_bf16(wf, bf[0][s], acc0, 0, 0, 0);
                        acc1 = __builtin_amdgcn_mfma_f32_16x16x32_bf16(wf, bf[1][s], acc1, 0, 0, 0);
                    }
                    // raw rows = ff*32 + sample (bank-uniform)
                    *(f32x4*)&raw[(ff * 32 + n16) * 52 + ty * 16 + quad * 4] = acc0;
                    *(f32x4*)&raw[(ff * 32 + 16 + n16) * 52 + ty * 16 + quad * 4] = acc1;
                }
            }

            // spline: lanes fi<nf handle (sample srow, feature 2p+fi)
            if (fi < nf) {
                int f = 2 * p + fi;
                const float* rp = &raw[(fi * 32 + srow) * 52];
                float xr = xc_pre[p];
                bool inside = (xr >= -TAILF) && (xr <= TAILF);
                float xcv = fminf(fmaxf(xr, -TAILF), TAILF);

                float uw[NBINS], uh[NBINS];
                {
                    f32x4 v0 = *(const f32x4*)(rp + 0);
                    f32x4 v1 = *(const f32x4*)(rp + 4);
                    f32x4 v2 = *(const f32x4*)(rp + 8);
                    f32x4 v3 = *(const f32x4*)(rp + 12);
                    f32x4 w0 = *(const f32x4*)(rp + 16);
                    f32x4 w1 = *(const f32x4*)(rp + 20);
                    f32x4 w2 = *(const f32x4*)(rp + 24);
                    f32x4 w3 = *(const f32x4*)(rp + 28);
#pragma unroll
                    for (int i = 0; i < 4; i++) {
                        uw[i] = v0[i]; uw[4 + i] = v1[i]; uw[8 + i] = v2[i]; uw[12 + i] = v3[i];
                        uh[i] = w0[i]; uh[4 + i] = w1[i]; uh[8 + i] = w2[i]; uh[12 + i] = w3[i];
                    }
                }
                float mw = -1e30f, mh = -1e30f;
#pragma unroll
                for (int i = 0; i < NBINS; i++) {
                    mw = fmaxf(mw, uw[i]); mh = fmaxf(mh, uh[i]);
                }
                float swv = 0.f, shv = 0.f;
#pragma unroll
                for (int i = 0; i < NBINS; i++) {
                    uw[i] = __expf(uw[i] - mw); swv += uw[i];
                    uh[i] = __expf(uh[i] - mh); shv += uh[i];
                }
                float isw = (1.f - NBINS * MIN_Wc) / swv;
                float ish = (1.f - NBINS * MIN_Hc) / shv;

                float cumw = 0.f, cumh = 0.f;
                float left = -TAILF, chl_run = -TAILF;
                float lw = -TAILF, wsel = 1.f, chl = -TAILF, hsel = 1.f;
                int idx = 0;
#pragma unroll
                for (int b = 0; b < NBINS; b++) {
                    float wb = MIN_Wc + uw[b] * isw;
                    float hb = MIN_Hc + uh[b] * ish;
                    cumw += wb; cumh += hb;
                    float cwr = (b == NBINS - 1) ? TAILF : 2.f * TAILF * cumw - TAILF;
                    float chr = (b == NBINS - 1) ? TAILF : 2.f * TAILF * cumh - TAILF;
                    bool inb = (xcv >= left) && ((xcv < cwr) || (b == NBINS - 1));
                    if (inb) { idx = b; lw = left; wsel = cwr - left; chl = chl_run; hsel = chr - chl_run; }
                    left = cwr; chl_run = chr;
                }
                float d0 = 1.f, d1 = 1.f;
                if (idx > 0) d0 = MIN_Dc + sp_softplus(rp[2 * NBINS + idx - 1]);
                if (idx < NBINS - 1) d1 = MIN_Dc + sp_softplus(rp[2 * NBINS + idx]);

                float delta = hsel / wsel;
                float th = (xcv - lw) / wsel;
                float omt = 1.f - th;
                float tomt = th * omt;
                float num = hsel * (delta * th * th + d0 * tomt);
                float den = delta + (d0 + d1 - 2.f * delta) * tomt;
                float y = chl + num / den;
                float dnum = delta * delta * (d1 * th * th + 2.f * delta * tomt + d0 * omt * omt);
                float lad = __logf(dnum) - 2.f * __logf(den);

                y = inside ? y : xr;
                lad = inside ? lad : 0.f;
                xs[srow * 17 + f] = y;
                lad_sum += lad;
            }
        }

        // ---- advance ring over pad frags 211..223 (keeps ring phase across layers)
#pragma unroll
        for (int d = 0; d < FRAGS_PAD - FRAGS_USED; d++) {
            (void)ldfrag();
        }

        wl += (size_t)FRAGS_PAD * FRAG_ELEMS;
    }

    // ---- epilogue: logdet (fi pair sums) + z write
    float v = lad_sum;
    v += __shfl_xor(v, 1);
    if (fi == 0) ldout[(size_t)sbase + srow] = v;

    for (int t = ln; t < SPW * FDIM; t += 64) {
        int s = t / FDIM, c = t % FDIM;
        zout[(size_t)sbase * FDIM + t] = xs[s * 17 + c];
    }
}

extern "C" void kernel_launch(void* const* d_in, const int* in_sizes, int n_in,
                              void* d_out, int out_size, void* d_ws, size_t ws_size,
                              hipStream_t stream) {
    const float* x  = (const float*)d_in[0];
    const float* Wi = (const float*)d_in[1];
    const float* bI = (const float*)d_in[2];
    const float* Wr = (const float*)d_in[3];
    const float* bR = (const float*)d_in[4];
    const float* Wo = (const float*)d_in[5];
    const float* bO = (const float*)d_in[6];

    bf16_t* wfrag = (bf16_t*)d_ws;
    // slack of RING frags (16 KB) after the last layer for tail prefetches
    size_t woff = ((size_t)WFRAG_TOTAL * 2 + (size_t)RING * FRAG_ELEMS * 2 + 255) & ~(size_t)255;
    float* bblob = (float*)((char*)d_ws + woff);
    float* zout  = (float*)d_out;
    float* ldout_final = zout + (size_t)BATCH * FDIM;

    const int totalP = WFRAG_TOTAL + BB_TOTAL;
    preproc_kernel<<<(totalP + 255) / 256, 256, 0, stream>>>(Wi, Wr, Wo, bI, bR, bO, wfrag, bblob);

    flow_kernel<<<BATCH / SPW, 64, 0, stream>>>(x, zout, ldout_final, wfrag, bblob);
}

// Round 4
// 381.232 us; speedup vs baseline: 2.0334x; 1.1475x over previous
//
#include <hip/hip_runtime.h>
#include <hip/hip_bf16.h>

#define FDIM 15
#define HDIM 128
#define LNUM 12
#define NBINS 16
#define MDIM 47
#define FM 705
#define BATCH 65536
#define TAILF 3.0f
#define MIN_Wc 0.001f
#define MIN_Hc 0.001f
#define MIN_Dc 0.001f

typedef __bf16 bf16_t;
typedef __attribute__((ext_vector_type(8))) __bf16 bf16x8;
typedef __attribute__((ext_vector_type(4))) __bf16 bf16x4;
typedef __attribute__((ext_vector_type(4))) float f32x4;

// sparse fragment schedule (degree-sorted hidden units):
//   init 8 | residual 4*23=92 | out 111  => 211 frags used.
// Padded to 224 per layer (multiple of RING=16): ring phase identical each
// layer; tail prefetches land on next layer's frags (wfrag contiguous).
#define FRAGS_USED 211
#define FRAGS_PAD 224
#define FRAG_ELEMS 512            // 64 lanes * 8 bf16 = 1 KB
#define RING 16
#define WFRAG_TOTAL (LNUM * FRAGS_PAD * FRAG_ELEMS)

// bias blob per layer: bI(128) | bR(512) | bOpad(15*48=720) = 1360 floats
#define BB_FLOATS 1360
#define BB_TOTAL (LNUM * BB_FLOATS)

#define SPW 32                    // samples per wave (2 N-tiles of 16)

// degree-sorted permutation: pos -> original hidden index.
__device__ __forceinline__ int perm_pos(int pos) {
    int r, o;
    if (pos < 20) { r = pos / 10; o = pos % 10; }
    else          { r = 2 + (pos - 20) / 9; o = (pos - 20) % 9; }
    return r + 14 * o;
}

__device__ __forceinline__ float sp_softplus(float u) {
    return (u > 20.f) ? u : __logf(1.f + __expf(u));
}

// ---------------- preproc: sparse-scheduled wfrag + permuted bias blob ----------------
__global__ void preproc_kernel(const float* __restrict__ Wi,
                               const float* __restrict__ Wr,
                               const float* __restrict__ Wo,
                               const float* __restrict__ bIg,
                               const float* __restrict__ bRg,
                               const float* __restrict__ bOg,
                               bf16_t* __restrict__ wfrag,
                               float* __restrict__ bblob) {
    const int RES_OFF[8] = {0, 1, 3, 5, 8, 11, 15, 19};
    const int OUT_OFF[15] = {0, 0, 3, 6, 9, 15, 21, 27, 36, 45, 54, 63, 75, 87, 99};
    const int OUT_CNT[15] = {0, 1, 1, 1, 2, 2, 2, 3, 3, 3, 3, 4, 4, 4, 4};

    int idx = blockIdx.x * blockDim.x + threadIdx.x;
    if (idx >= WFRAG_TOTAL) {
        int t = idx - WFRAG_TOTAL;
        if (t >= BB_TOTAL) return;
        int l = t / BB_FLOATS, r = t % BB_FLOATS;
        float v;
        if (r < 128) v = bIg[l * HDIM + perm_pos(r)];
        else if (r < 640) {
            int mat = (r - 128) >> 7, pos = (r - 128) & 127;
            v = bRg[(l * 4 + mat) * HDIM + perm_pos(pos)];
        } else {
            int q = r - 640, f = q / 48, j = q % 48;
            v = (j < 47) ? bOg[(size_t)l * FM + f * MDIM + j] : 0.f;
        }
        bblob[t] = v;
        return;
    }
    int j = idx & 7;
    int lane = (idx >> 3) & 63;
    int fg = idx >> 9;
    int g = fg % FRAGS_PAD;
    int l = fg / FRAGS_PAD;
    int quad = lane >> 4, n16 = lane & 15;
    int kk = quad * 8 + j;
    float val = 0.f;
    if (g < 8) {
        int n_orig = perm_pos(g * 16 + n16);
        if (kk < FDIM && (n_orig % 14) >= kk)
            val = Wi[(l * HDIM + n_orig) * FDIM + kk];
    } else if (g < 100) {
        int gg = g - 8;
        int mat = gg / 23, r = gg % 23;
        int mt = 7;
        while (mt > 0 && RES_OFF[mt] > r) mt--;
        int s = r - RES_OFF[mt];
        int j_orig = perm_pos(mt * 16 + n16);
        int k_orig = perm_pos(s * 32 + kk);
        if ((j_orig % 14) >= (k_orig % 14))
            val = Wr[((size_t)(l * 4 + mat) * HDIM + j_orig) * HDIM + k_orig];
    } else if (g < 211) {
        int gg = g - 100;
        int f = 14;
        while (f > 1 && OUT_OFF[f] > gg) f--;
        int q = gg - OUT_OFF[f];
        int cnt = OUT_CNT[f];
        int ty = q / cnt, s = q % cnt;
        int k_orig = perm_pos(s * 32 + kk);
        int o = (ty < 2) ? (f * MDIM + ty * 16 + n16)
                         : ((n16 < 15) ? (f * MDIM + 32 + n16) : -1);
        if (o >= 0 && f > (k_orig % 14))
            val = Wo[((size_t)l * FM + o) * HDIM + k_orig];
    }
    // g in [211,224): zero pad
    wfrag[idx] = (bf16_t)val;
}

// ---------------- fused 12-layer flow kernel ----------------
// One wave per block (64 threads): fully independent, ZERO barriers.
// Weights stream global->VGPR through a 16-deep register ring.
// x persists in LDS across layers; logdet persists in a register.
__global__ __launch_bounds__(64, 2) void flow_kernel(
    const float* __restrict__ xin,
    float* __restrict__ zout,
    float* __restrict__ ldout,
    const bf16_t* __restrict__ wfrag,
    const float* __restrict__ bblob) {

    constexpr int RES_CNT_C[8] = {1, 2, 2, 3, 3, 4, 4, 4};
    constexpr int OUT_CNT_C[15] = {0, 1, 1, 1, 2, 2, 2, 3, 3, 3, 3, 4, 4, 4, 4};

    __shared__ __align__(16) float xs[SPW * 17];          // 2176 B
    __shared__ __align__(16) unsigned char uni[13312];    // Bst[32][136] bf16 (8704) U raw[2][32][52] f32 (13312)

    const int ln = threadIdx.x;                 // 0..63
    const int quad = ln >> 4, n16 = ln & 15;
    const int fi = ln & 1, srow = ln >> 1;
    const int sbase = blockIdx.x * SPW;

    bf16_t* Bst = (bf16_t*)uni;
    float*  raw = (float*)uni;

    // load x (32 samples x 15), coalesced
    for (int t = ln; t < SPW * FDIM; t += 64) {
        int s = t / FDIM, c = t % FDIM;
        xs[s * 17 + c] = xin[(size_t)sbase * FDIM + t];
    }

    // ---- weight ring prologue: frags 0..15 of layer 0 in flight
    const bf16_t* wl = wfrag;
    bf16x8 Q[RING];
#pragma unroll
    for (int j = 0; j < RING; j++)
        Q[j] = *((const bf16x8*)(wl + (size_t)j * FRAG_ELEMS) + ln);

    float lad_sum = 0.f;
    bf16x8 bf[2][4];      // staged act B-frags (k-tiles in sorted hidden space)
    f32x4 h[2][8];        // persistent carry: rows = hidden (sorted), col = sample n16

#pragma unroll 1
    for (int l = 0; l < LNUM; l++) {
        const float* bias = bblob + l * BB_FLOATS;

        // spline x-inputs (reversed frame), snapshot BEFORE any spline write
        float xc_pre[8];
#pragma unroll
        for (int p = 0; p < 8; p++) {
            int f = 2 * p + fi;
            xc_pre[p] = xs[srow * 17 + ((f < FDIM) ? (14 - f) : 0)];
        }
        // init-GEMM act B fragments from reversed xs, K padded 15->32
        bf16x8 a0[2];
#pragma unroll
        for (int T = 0; T < 2; T++)
#pragma unroll
            for (int j = 0; j < 8; j++) {
                int k = quad * 8 + j;
                a0[T][j] = (bf16_t)((k < FDIM) ? xs[(T * 16 + n16) * 17 + 14 - k] : 0.f);
            }

        // ---- per-layer frag consumption with ring refill (no barriers)
        int fp = 0;
        auto ldfrag = [&]() -> bf16x8 {
            bf16x8 r = Q[fp & (RING - 1)];
            Q[fp & (RING - 1)] =
                *((const bf16x8*)(wl + (size_t)(fp + RING) * FRAG_ELEMS) + ln);
            fp++;
            return r;
        };

        auto packmt = [&](int mt, f32x4 c0, f32x4 c1, bool relu) {
#pragma unroll
            for (int T = 0; T < 2; T++) {
                f32x4 c = T ? c1 : c0;
                bf16x4 pk;
#pragma unroll
                for (int r2 = 0; r2 < 4; r2++) {
                    float v = c[r2];
                    if (relu) v = fmaxf(v, 0.f);
                    pk[r2] = (bf16_t)v;
                }
                *(bf16x4*)&Bst[(T * 16 + n16) * 136 + mt * 16 + quad * 4] = pk;
            }
        };
        auto readbf = [&]() {
#pragma unroll
            for (int T = 0; T < 2; T++)
#pragma unroll
                for (int s = 0; s < 4; s++)
                    bf[T][s] = *(const bf16x8*)&Bst[(T * 16 + n16) * 136 + s * 32 + quad * 8];
        };

        // ---- init GEMM (frags 0..7), pack relu(h)
#pragma unroll
        for (int mt = 0; mt < 8; mt++) {
            f32x4 bbv = *(const f32x4*)&bias[mt * 16 + quad * 4];
            bf16x8 wf = ldfrag();
            f32x4 c0 = __builtin_amdgcn_mfma_f32_16x16x32_bf16(wf, a0[0], bbv, 0, 0, 0);
            f32x4 c1 = __builtin_amdgcn_mfma_f32_16x16x32_bf16(wf, a0[1], bbv, 0, 0, 0);
            h[0][mt] = c0; h[1][mt] = c1;
            packmt(mt, c0, c1, true);
        }
        readbf();

        // ---- residual GEMMs fused with pack (frags 8..99)
        auto gemm_pack = [&](const float* bm, bool addto, bool relu) {
#pragma unroll
            for (int mt = 0; mt < 8; mt++) {
                f32x4 bbv = *(const f32x4*)&bm[mt * 16 + quad * 4];
                f32x4 acc0 = addto ? (h[0][mt] + bbv) : bbv;
                f32x4 acc1 = addto ? (h[1][mt] + bbv) : bbv;
#pragma unroll
                for (int s = 0; s < RES_CNT_C[mt]; s++) {
                    bf16x8 wf = ldfrag();
                    acc0 = __builtin_amdgcn_mfma_f32_16x16x32_bf16(wf, bf[0][s], acc0, 0, 0, 0);
                    acc1 = __builtin_amdgcn_mfma_f32_16x16x32_bf16(wf, bf[1][s], acc1, 0, 0, 0);
                }
                if (addto) { h[0][mt] = acc0; h[1][mt] = acc1; }
                packmt(mt, acc0, acc1, relu);
            }
            readbf();
        };

        gemm_pack(bias + 128 + 0 * HDIM, false, true);   // t = W1a . relu(h)
        gemm_pack(bias + 128 + 1 * HDIM, true,  true);   // h += W1b . relu(t)
        gemm_pack(bias + 128 + 2 * HDIM, false, true);   // t = W2a . relu(h)
        gemm_pack(bias + 128 + 3 * HDIM, true,  false);  // h += W2b . relu(t); pack h

        // ---- out GEMM (frags 100..210) in 2-feature rounds + spline
        const float* bO48 = bias + 640;

#pragma unroll
        for (int p = 0; p < 8; p++) {
            const int nf = (p < 7) ? 2 : 1;
#pragma unroll
            for (int ff = 0; ff < 2; ff++) {
                if (ff >= nf) break;
                const int f = 2 * p + ff;
                const int cnt = OUT_CNT_C[f];
#pragma unroll
                for (int ty = 0; ty < 3; ty++) {
                    f32x4 acc0 = *(const f32x4*)&bO48[f * 48 + ty * 16 + quad * 4];
                    f32x4 acc1 = acc0;
#pragma unroll
                    for (int s = 0; s < cnt; s++) {
                        bf16x8 wf = ldfrag();
                        acc0 = __builtin_amdgcn_mfma_f32_16x16x32_bf16(wf, bf[0][s], acc0, 0, 0, 0);
                        acc1 = __builtin_amdgcn_mfma_f32_16x16x32_bf16(wf, bf[1][s], acc1, 0, 0, 0);
                    }
                    // raw rows = ff*32 + sample (bank-uniform)
                    *(f32x4*)&raw[(ff * 32 + n16) * 52 + ty * 16 + quad * 4] = acc0;
                    *(f32x4*)&raw[(ff * 32 + 16 + n16) * 52 + ty * 16 + quad * 4] = acc1;
                }
            }

            // spline: lanes fi<nf handle (sample srow, feature 2p+fi)
            if (fi < nf) {
                int f = 2 * p + fi;
                const float* rp = &raw[(fi * 32 + srow) * 52];
                float xr = xc_pre[p];
                bool inside = (xr >= -TAILF) && (xr <= TAILF);
                float xcv = fminf(fmaxf(xr, -TAILF), TAILF);

                // ALL raw reads upfront (uw, uh, d): no late data-dependent LDS read
                float uw[NBINS], uh[NBINS], dv[NBINS];
                {
                    f32x4 v0 = *(const f32x4*)(rp + 0);
                    f32x4 v1 = *(const f32x4*)(rp + 4);
                    f32x4 v2 = *(const f32x4*)(rp + 8);
                    f32x4 v3 = *(const f32x4*)(rp + 12);
                    f32x4 w0 = *(const f32x4*)(rp + 16);
                    f32x4 w1 = *(const f32x4*)(rp + 20);
                    f32x4 w2 = *(const f32x4*)(rp + 24);
                    f32x4 w3 = *(const f32x4*)(rp + 28);
                    f32x4 e0 = *(const f32x4*)(rp + 32);
                    f32x4 e1 = *(const f32x4*)(rp + 36);
                    f32x4 e2 = *(const f32x4*)(rp + 40);
                    f32x4 e3 = *(const f32x4*)(rp + 44);
#pragma unroll
                    for (int i = 0; i < 4; i++) {
                        uw[i] = v0[i]; uw[4 + i] = v1[i]; uw[8 + i] = v2[i]; uw[12 + i] = v3[i];
                        uh[i] = w0[i]; uh[4 + i] = w1[i]; uh[8 + i] = w2[i]; uh[12 + i] = w3[i];
                        dv[i] = e0[i]; dv[4 + i] = e1[i]; dv[8 + i] = e2[i]; dv[12 + i] = e3[i];
                    }
                }

                // max via pairwise trees (fusable to v_max3)
                float mw, mh;
                {
                    float a0_ = fmaxf(uw[0], uw[1]),   a1_ = fmaxf(uw[2], uw[3]);
                    float a2_ = fmaxf(uw[4], uw[5]),   a3_ = fmaxf(uw[6], uw[7]);
                    float a4_ = fmaxf(uw[8], uw[9]),   a5_ = fmaxf(uw[10], uw[11]);
                    float a6_ = fmaxf(uw[12], uw[13]), a7_ = fmaxf(uw[14], uw[15]);
                    mw = fmaxf(fmaxf(fmaxf(a0_, a1_), fmaxf(a2_, a3_)),
                               fmaxf(fmaxf(a4_, a5_), fmaxf(a6_, a7_)));
                    float b0_ = fmaxf(uh[0], uh[1]),   b1_ = fmaxf(uh[2], uh[3]);
                    float b2_ = fmaxf(uh[4], uh[5]),   b3_ = fmaxf(uh[6], uh[7]);
                    float b4_ = fmaxf(uh[8], uh[9]),   b5_ = fmaxf(uh[10], uh[11]);
                    float b6_ = fmaxf(uh[12], uh[13]), b7_ = fmaxf(uh[14], uh[15]);
                    mh = fmaxf(fmaxf(fmaxf(b0_, b1_), fmaxf(b2_, b3_)),
                               fmaxf(fmaxf(b4_, b5_), fmaxf(b6_, b7_)));
                }

                float ew[NBINS], eh[NBINS];
#pragma unroll
                for (int i = 0; i < NBINS; i++) {
                    ew[i] = __expf(uw[i] - mw);
                    eh[i] = __expf(uh[i] - mh);
                }
                // sum trees
                float swv, shv;
                {
                    float s0 = ew[0] + ew[1], s1 = ew[2] + ew[3];
                    float s2 = ew[4] + ew[5], s3 = ew[6] + ew[7];
                    float s4 = ew[8] + ew[9], s5 = ew[10] + ew[11];
                    float s6 = ew[12] + ew[13], s7 = ew[14] + ew[15];
                    swv = ((s0 + s1) + (s2 + s3)) + ((s4 + s5) + (s6 + s7));
                    float t0 = eh[0] + eh[1], t1 = eh[2] + eh[3];
                    float t2 = eh[4] + eh[5], t3 = eh[6] + eh[7];
                    float t4 = eh[8] + eh[9], t5 = eh[10] + eh[11];
                    float t6 = eh[12] + eh[13], t7 = eh[14] + eh[15];
                    shv = ((t0 + t1) + (t2 + t3)) + ((t4 + t5) + (t6 + t7));
                }

                // pre-scaled widths: wb2[i] = x-width of bin i (2*TAIL units)
                const float mwc2 = 2.f * TAILF * MIN_Wc;
                float isw2 = (2.f * TAILF) * (1.f - NBINS * MIN_Wc) * __builtin_amdgcn_rcpf(swv);
                float ish2 = (2.f * TAILF) * (1.f - NBINS * MIN_Hc) * __builtin_amdgcn_rcpf(shv);
                float wb2[NBINS], hb2[NBINS];
#pragma unroll
                for (int i = 0; i < NBINS; i++) {
                    wb2[i] = fmaf(ew[i], isw2, mwc2);
                    hb2[i] = fmaf(eh[i], ish2, mwc2);
                }

                // add-scan: select last bin edge <= xcv (monotone)
                float cwr = -TAILF, chr = -TAILF;
                float lw = -TAILF, chl = -TAILF;
                float curw = wb2[0], curh = hb2[0];
                float d0r = dv[0], d1r = dv[0];
                bool gt0 = false, lt15 = true;
#pragma unroll
                for (int b = 0; b < NBINS - 1; b++) {
                    cwr += wb2[b]; chr += hb2[b];
                    bool v = (xcv >= cwr);
                    if (b == 0) gt0 = v;
                    if (b == NBINS - 2) lt15 = !v;
                    lw   = v ? cwr : lw;
                    chl  = v ? chr : chl;
                    curw = v ? wb2[b + 1] : curw;
                    curh = v ? hb2[b + 1] : curh;
                    d0r  = v ? dv[b] : d0r;
                    d1r  = v ? dv[b + 1] : d1r;
                }

                float spl0 = sp_softplus(d0r), spl1 = sp_softplus(d1r);
                float d0 = gt0 ? (MIN_Dc + spl0) : 1.f;
                float d1 = lt15 ? (MIN_Dc + spl1) : 1.f;

                float rw = __builtin_amdgcn_rcpf(curw);
                float delta = curh * rw;
                float th = (xcv - lw) * rw;
                float omt = 1.f - th;
                float tomt = th * omt;
                float num = curh * (delta * th * th + d0 * tomt);
                float den = delta + (d0 + d1 - 2.f * delta) * tomt;
                float y = chl + num * __builtin_amdgcn_rcpf(den);
                float dnum = delta * delta * (d1 * th * th + 2.f * delta * tomt + d0 * omt * omt);
                float lad = 0.69314718055994531f * (__log2f(dnum) - 2.f * __log2f(den));

                y = inside ? y : xr;
                lad = inside ? lad : 0.f;
                xs[srow * 17 + f] = y;
                lad_sum += lad;
            }
        }

        // ---- advance ring over pad frags 211..223 (keeps ring phase across layers)
#pragma unroll
        for (int d = 0; d < FRAGS_PAD - FRAGS_USED; d++) {
            (void)ldfrag();
        }

        wl += (size_t)FRAGS_PAD * FRAG_ELEMS;
    }

    // ---- epilogue: logdet (fi pair sums) + z write
    float v = lad_sum;
    v += __shfl_xor(v, 1);
    if (fi == 0) ldout[(size_t)sbase + srow] = v;

    for (int t = ln; t < SPW * FDIM; t += 64) {
        int s = t / FDIM, c = t % FDIM;
        zout[(size_t)sbase * FDIM + t] = xs[s * 17 + c];
    }
}

extern "C" void kernel_launch(void* const* d_in, const int* in_sizes, int n_in,
                              void* d_out, int out_size, void* d_ws, size_t ws_size,
                              hipStream_t stream) {
    const float* x  = (const float*)d_in[0];
    const float* Wi = (const float*)d_in[1];
    const float* bI = (const float*)d_in[2];
    const float* Wr = (const float*)d_in[3];
    const float* bR = (const float*)d_in[4];
    const float* Wo = (const float*)d_in[5];
    const float* bO = (const float*)d_in[6];

    bf16_t* wfrag = (bf16_t*)d_ws;
    // slack of RING frags (16 KB) after the last layer for tail prefetches
    size_t woff = ((size_t)WFRAG_TOTAL * 2 + (size_t)RING * FRAG_ELEMS * 2 + 255) & ~(size_t)255;
    float* bblob = (float*)((char*)d_ws + woff);
    float* zout  = (float*)d_out;
    float* ldout_final = zout + (size_t)BATCH * FDIM;

    const int totalP = WFRAG_TOTAL + BB_TOTAL;
    preproc_kernel<<<(totalP + 255) / 256, 256, 0, stream>>>(Wi, Wr, Wo, bI, bR, bO, wfrag, bblob);

    flow_kernel<<<BATCH / SPW, 64, 0, stream>>>(x, zout, ldout_final, wfrag, bblob);
}

// Round 5
// 372.523 us; speedup vs baseline: 2.0809x; 1.0234x over previous
//
#include <hip/hip_runtime.h>
#include <hip/hip_bf16.h>

#define FDIM 15
#define HDIM 128
#define LNUM 12
#define NBINS 16
#define MDIM 47
#define FM 705
#define BATCH 65536
#define TAILF 3.0f
#define MIN_Wc 0.001f
#define MIN_Hc 0.001f
#define MIN_Dc 0.001f

typedef __bf16 bf16_t;
typedef __attribute__((ext_vector_type(8))) __bf16 bf16x8;
typedef __attribute__((ext_vector_type(4))) __bf16 bf16x4;
typedef __attribute__((ext_vector_type(4))) float f32x4;

// sparse fragment schedule (degree-sorted hidden units):
//   init 8 | residual 4*23=92 | out 111  => 211 frags used.
// Padded to 224 per layer (multiple of RING=16): ring phase identical each
// layer; tail prefetches land on next layer's frags (wfrag contiguous).
#define FRAGS_USED 211
#define FRAGS_PAD 224
#define FRAG_ELEMS 512            // 64 lanes * 8 bf16 = 1 KB
#define RING 16
#define WFRAG_TOTAL (LNUM * FRAGS_PAD * FRAG_ELEMS)

// bias blob per layer: bI(128) | bR(512) | bOpad(15*48=720) = 1360 floats
#define BB_FLOATS 1360
#define BB_TOTAL (LNUM * BB_FLOATS)

#define SPW 32                    // samples per wave (2 N-tiles of 16)

// degree-sorted permutation: pos -> original hidden index.
__device__ __forceinline__ int perm_pos(int pos) {
    int r, o;
    if (pos < 20) { r = pos / 10; o = pos % 10; }
    else          { r = 2 + (pos - 20) / 9; o = (pos - 20) % 9; }
    return r + 14 * o;
}

__device__ __forceinline__ float sp_softplus(float u) {
    return (u > 20.f) ? u : __logf(1.f + __expf(u));
}

// ---------------- preproc: sparse-scheduled wfrag + permuted bias blob ----------------
__global__ void preproc_kernel(const float* __restrict__ Wi,
                               const float* __restrict__ Wr,
                               const float* __restrict__ Wo,
                               const float* __restrict__ bIg,
                               const float* __restrict__ bRg,
                               const float* __restrict__ bOg,
                               bf16_t* __restrict__ wfrag,
                               float* __restrict__ bblob) {
    const int RES_OFF[8] = {0, 1, 3, 5, 8, 11, 15, 19};
    const int OUT_OFF[15] = {0, 0, 3, 6, 9, 15, 21, 27, 36, 45, 54, 63, 75, 87, 99};
    const int OUT_CNT[15] = {0, 1, 1, 1, 2, 2, 2, 3, 3, 3, 3, 4, 4, 4, 4};

    int idx = blockIdx.x * blockDim.x + threadIdx.x;
    if (idx >= WFRAG_TOTAL) {
        int t = idx - WFRAG_TOTAL;
        if (t >= BB_TOTAL) return;
        int l = t / BB_FLOATS, r = t % BB_FLOATS;
        float v;
        if (r < 128) v = bIg[l * HDIM + perm_pos(r)];
        else if (r < 640) {
            int mat = (r - 128) >> 7, pos = (r - 128) & 127;
            v = bRg[(l * 4 + mat) * HDIM + perm_pos(pos)];
        } else {
            int q = r - 640, f = q / 48, j = q % 48;
            v = (j < 47) ? bOg[(size_t)l * FM + f * MDIM + j] : 0.f;
        }
        bblob[t] = v;
        return;
    }
    int j = idx & 7;
    int lane = (idx >> 3) & 63;
    int fg = idx >> 9;
    int g = fg % FRAGS_PAD;
    int l = fg / FRAGS_PAD;
    int quad = lane >> 4, n16 = lane & 15;
    int kk = quad * 8 + j;
    float val = 0.f;
    if (g < 8) {
        int n_orig = perm_pos(g * 16 + n16);
        if (kk < FDIM && (n_orig % 14) >= kk)
            val = Wi[(l * HDIM + n_orig) * FDIM + kk];
    } else if (g < 100) {
        int gg = g - 8;
        int mat = gg / 23, r = gg % 23;
        int mt = 7;
        while (mt > 0 && RES_OFF[mt] > r) mt--;
        int s = r - RES_OFF[mt];
        int j_orig = perm_pos(mt * 16 + n16);
        int k_orig = perm_pos(s * 32 + kk);
        if ((j_orig % 14) >= (k_orig % 14))
            val = Wr[((size_t)(l * 4 + mat) * HDIM + j_orig) * HDIM + k_orig];
    } else if (g < 211) {
        int gg = g - 100;
        int f = 14;
        while (f > 1 && OUT_OFF[f] > gg) f--;
        int q = gg - OUT_OFF[f];
        int cnt = OUT_CNT[f];
        int ty = q / cnt, s = q % cnt;
        int k_orig = perm_pos(s * 32 + kk);
        int o = (ty < 2) ? (f * MDIM + ty * 16 + n16)
                         : ((n16 < 15) ? (f * MDIM + 32 + n16) : -1);
        if (o >= 0 && f > (k_orig % 14))
            val = Wo[((size_t)l * FM + o) * HDIM + k_orig];
    }
    // g in [211,224): zero pad
    wfrag[idx] = (bf16_t)val;
}

// ---------------- fused 12-layer flow kernel ----------------
// One wave per block (64 threads): fully independent, ZERO barriers.
// Weights stream global->VGPR through a 16-deep register ring.
// x persists in LDS across layers; logdet persists in a register.
// B-frag reads are issued per-mt-pair (bfn staging) so the phase boundary
// only drains the last pair's DS ops, not the whole 24-op queue.
__global__ __launch_bounds__(64, 2) void flow_kernel(
    const float* __restrict__ xin,
    float* __restrict__ zout,
    float* __restrict__ ldout,
    const bf16_t* __restrict__ wfrag,
    const float* __restrict__ bblob) {

    constexpr int RES_CNT_C[8] = {1, 2, 2, 3, 3, 4, 4, 4};
    constexpr int OUT_CNT_C[15] = {0, 1, 1, 1, 2, 2, 2, 3, 3, 3, 3, 4, 4, 4, 4};

    __shared__ __align__(16) float xs[SPW * 17];          // 2176 B
    __shared__ __align__(16) unsigned char uni[13312];    // Bst[32][136] bf16 (8704) U raw[2][32][52] f32 (13312)

    const int ln = threadIdx.x;                 // 0..63
    const int quad = ln >> 4, n16 = ln & 15;
    const int fi = ln & 1, srow = ln >> 1;
    const int sbase = blockIdx.x * SPW;

    bf16_t* Bst = (bf16_t*)uni;
    float*  raw = (float*)uni;

    // load x (32 samples x 15), coalesced
    for (int t = ln; t < SPW * FDIM; t += 64) {
        int s = t / FDIM, c = t % FDIM;
        xs[s * 17 + c] = xin[(size_t)sbase * FDIM + t];
    }

    // ---- weight ring prologue: frags 0..15 of layer 0 in flight
    const bf16_t* wl = wfrag;
    bf16x8 Q[RING];
#pragma unroll
    for (int j = 0; j < RING; j++)
        Q[j] = *((const bf16x8*)(wl + (size_t)j * FRAG_ELEMS) + ln);

    float lad_sum = 0.f;
    bf16x8 bf[2][4];      // staged act B-frags (k-tiles in sorted hidden space)
    bf16x8 bfn[2][4];     // next-phase B-frags (read per-mt-pair, early)
    f32x4 h[2][8];        // persistent carry: rows = hidden (sorted), col = sample n16

#pragma unroll 1
    for (int l = 0; l < LNUM; l++) {
        const float* bias = bblob + l * BB_FLOATS;

        // spline x-inputs (reversed frame), snapshot BEFORE any spline write
        float xc_pre[8];
#pragma unroll
        for (int p = 0; p < 8; p++) {
            int f = 2 * p + fi;
            xc_pre[p] = xs[srow * 17 + ((f < FDIM) ? (14 - f) : 0)];
        }
        // init-GEMM act B fragments from reversed xs, K padded 15->32
        bf16x8 a0[2];
#pragma unroll
        for (int T = 0; T < 2; T++)
#pragma unroll
            for (int j = 0; j < 8; j++) {
                int k = quad * 8 + j;
                a0[T][j] = (bf16_t)((k < FDIM) ? xs[(T * 16 + n16) * 17 + 14 - k] : 0.f);
            }

        // ---- per-layer frag consumption with ring refill (no barriers)
        int fp = 0;
        auto ldfrag = [&]() -> bf16x8 {
            bf16x8 r = Q[fp & (RING - 1)];
            Q[fp & (RING - 1)] =
                *((const bf16x8*)(wl + (size_t)(fp + RING) * FRAG_ELEMS) + ln);
            fp++;
            return r;
        };

        auto packmt = [&](int mt, f32x4 c0, f32x4 c1, bool relu) {
#pragma unroll
            for (int T = 0; T < 2; T++) {
                f32x4 c = T ? c1 : c0;
                bf16x4 pk;
#pragma unroll
                for (int r2 = 0; r2 < 4; r2++) {
                    float v = c[r2];
                    if (relu) v = fmaxf(v, 0.f);
                    pk[r2] = (bf16_t)v;
                }
                *(bf16x4*)&Bst[(T * 16 + n16) * 136 + mt * 16 + quad * 4] = pk;
            }
        };
        // read one next-phase B-frag pair (k-tile s2) right after its writes
        auto readpair = [&](int s2) {
#pragma unroll
            for (int T = 0; T < 2; T++)
                bfn[T][s2] = *(const bf16x8*)&Bst[(T * 16 + n16) * 136 + s2 * 32 + quad * 8];
        };
        auto commitbf = [&]() {
#pragma unroll
            for (int T = 0; T < 2; T++)
#pragma unroll
                for (int s = 0; s < 4; s++) bf[T][s] = bfn[T][s];
        };

        // ---- init GEMM (frags 0..7), pack relu(h)
#pragma unroll
        for (int mt = 0; mt < 8; mt++) {
            f32x4 bbv = *(const f32x4*)&bias[mt * 16 + quad * 4];
            bf16x8 wf = ldfrag();
            f32x4 c0 = __builtin_amdgcn_mfma_f32_16x16x32_bf16(wf, a0[0], bbv, 0, 0, 0);
            f32x4 c1 = __builtin_amdgcn_mfma_f32_16x16x32_bf16(wf, a0[1], bbv, 0, 0, 0);
            h[0][mt] = c0; h[1][mt] = c1;
            packmt(mt, c0, c1, true);
            if (mt & 1) readpair(mt >> 1);
        }
        commitbf();

        // ---- residual GEMMs fused with pack (frags 8..99)
        auto gemm_pack = [&](const float* bm, bool addto, bool relu) {
#pragma unroll
            for (int mt = 0; mt < 8; mt++) {
                f32x4 bbv = *(const f32x4*)&bm[mt * 16 + quad * 4];
                f32x4 acc0 = addto ? (h[0][mt] + bbv) : bbv;
                f32x4 acc1 = addto ? (h[1][mt] + bbv) : bbv;
#pragma unroll
                for (int s = 0; s < RES_CNT_C[mt]; s++) {
                    bf16x8 wf = ldfrag();
                    acc0 = __builtin_amdgcn_mfma_f32_16x16x32_bf16(wf, bf[0][s], acc0, 0, 0, 0);
                    acc1 = __builtin_amdgcn_mfma_f32_16x16x32_bf16(wf, bf[1][s], acc1, 0, 0, 0);
                }
                if (addto) { h[0][mt] = acc0; h[1][mt] = acc1; }
                packmt(mt, acc0, acc1, relu);
                if (mt & 1) readpair(mt >> 1);
            }
            commitbf();
        };

        gemm_pack(bias + 128 + 0 * HDIM, false, true);   // t = W1a . relu(h)
        gemm_pack(bias + 128 + 1 * HDIM, true,  true);   // h += W1b . relu(t)
        gemm_pack(bias + 128 + 2 * HDIM, false, true);   // t = W2a . relu(h)
        gemm_pack(bias + 128 + 3 * HDIM, true,  false);  // h += W2b . relu(t); pack h

        // ---- out GEMM (frags 100..210) in 2-feature rounds + spline
        const float* bO48 = bias + 640;

#pragma unroll
        for (int p = 0; p < 8; p++) {
            const int nf = (p < 7) ? 2 : 1;
#pragma unroll
            for (int ff = 0; ff < 2; ff++) {
                if (ff >= nf) break;
                const int f = 2 * p + ff;
                const int cnt = OUT_CNT_C[f];
#pragma unroll
                for (int ty = 0; ty < 3; ty++) {
                    f32x4 acc0 = *(const f32x4*)&bO48[f * 48 + ty * 16 + quad * 4];
                    f32x4 acc1 = acc0;
#pragma unroll
                    for (int s = 0; s < cnt; s++) {
                        bf16x8 wf = ldfrag();
                        acc0 = __builtin_amdgcn_mfma_f32_16x16x32_bf16(wf, bf[0][s], acc0, 0, 0, 0);
                        acc1 = __builtin_amdgcn_mfma_f32_16x16x32_bf16(wf, bf[1][s], acc1, 0, 0, 0);
                    }
                    // raw rows = ff*32 + sample (bank-uniform)
                    *(f32x4*)&raw[(ff * 32 + n16) * 52 + ty * 16 + quad * 4] = acc0;
                    *(f32x4*)&raw[(ff * 32 + 16 + n16) * 52 + ty * 16 + quad * 4] = acc1;
                }
            }

            // spline: lanes fi<nf handle (sample srow, feature 2p+fi)
            if (fi < nf) {
                int f = 2 * p + fi;
                const float* rp = &raw[(fi * 32 + srow) * 52];
                float xr = xc_pre[p];
                bool inside = (xr >= -TAILF) && (xr <= TAILF);
                float xcv = fminf(fmaxf(xr, -TAILF), TAILF);

                // ALL raw reads upfront (uw, uh, d): no late data-dependent LDS read
                float uw[NBINS], uh[NBINS], dv[NBINS];
                {
                    f32x4 v0 = *(const f32x4*)(rp + 0);
                    f32x4 v1 = *(const f32x4*)(rp + 4);
                    f32x4 v2 = *(const f32x4*)(rp + 8);
                    f32x4 v3 = *(const f32x4*)(rp + 12);
                    f32x4 w0 = *(const f32x4*)(rp + 16);
                    f32x4 w1 = *(const f32x4*)(rp + 20);
                    f32x4 w2 = *(const f32x4*)(rp + 24);
                    f32x4 w3 = *(const f32x4*)(rp + 28);
                    f32x4 e0 = *(const f32x4*)(rp + 32);
                    f32x4 e1 = *(const f32x4*)(rp + 36);
                    f32x4 e2 = *(const f32x4*)(rp + 40);
                    f32x4 e3 = *(const f32x4*)(rp + 44);
#pragma unroll
                    for (int i = 0; i < 4; i++) {
                        uw[i] = v0[i]; uw[4 + i] = v1[i]; uw[8 + i] = v2[i]; uw[12 + i] = v3[i];
                        uh[i] = w0[i]; uh[4 + i] = w1[i]; uh[8 + i] = w2[i]; uh[12 + i] = w3[i];
                        dv[i] = e0[i]; dv[4 + i] = e1[i]; dv[8 + i] = e2[i]; dv[12 + i] = e3[i];
                    }
                }

                // softmax WITHOUT max-subtraction: exp(u)/sum == exp(u-m)/sum',
                // and MADE outputs are bounded (|u| ~ 2) so no overflow risk.
                float ew[NBINS], eh[NBINS];
#pragma unroll
                for (int i = 0; i < NBINS; i++) {
                    ew[i] = __expf(uw[i]);
                    eh[i] = __expf(uh[i]);
                }
                // sum trees
                float swv, shv;
                {
                    float s0 = ew[0] + ew[1], s1 = ew[2] + ew[3];
                    float s2 = ew[4] + ew[5], s3 = ew[6] + ew[7];
                    float s4 = ew[8] + ew[9], s5 = ew[10] + ew[11];
                    float s6 = ew[12] + ew[13], s7 = ew[14] + ew[15];
                    swv = ((s0 + s1) + (s2 + s3)) + ((s4 + s5) + (s6 + s7));
                    float t0 = eh[0] + eh[1], t1 = eh[2] + eh[3];
                    float t2 = eh[4] + eh[5], t3 = eh[6] + eh[7];
                    float t4 = eh[8] + eh[9], t5 = eh[10] + eh[11];
                    float t6 = eh[12] + eh[13], t7 = eh[14] + eh[15];
                    shv = ((t0 + t1) + (t2 + t3)) + ((t4 + t5) + (t6 + t7));
                }

                // pre-scaled widths: wb2[i] = x-width of bin i (2*TAIL units)
                const float mwc2 = 2.f * TAILF * MIN_Wc;
                float isw2 = (2.f * TAILF) * (1.f - NBINS * MIN_Wc) * __builtin_amdgcn_rcpf(swv);
                float ish2 = (2.f * TAILF) * (1.f - NBINS * MIN_Hc) * __builtin_amdgcn_rcpf(shv);
                float wb2[NBINS], hb2[NBINS];
#pragma unroll
                for (int i = 0; i < NBINS; i++) {
                    wb2[i] = fmaf(ew[i], isw2, mwc2);
                    hb2[i] = fmaf(eh[i], ish2, mwc2);
                }

                // add-scan: select last bin edge <= xcv (monotone)
                float cwr = -TAILF, chr = -TAILF;
                float lw = -TAILF, chl = -TAILF;
                float curw = wb2[0], curh = hb2[0];
                float d0r = dv[0], d1r = dv[0];
                bool gt0 = false, lt15 = true;
#pragma unroll
                for (int b = 0; b < NBINS - 1; b++) {
                    cwr += wb2[b]; chr += hb2[b];
                    bool v = (xcv >= cwr);
                    if (b == 0) gt0 = v;
                    if (b == NBINS - 2) lt15 = !v;
                    lw   = v ? cwr : lw;
                    chl  = v ? chr : chl;
                    curw = v ? wb2[b + 1] : curw;
                    curh = v ? hb2[b + 1] : curh;
                    d0r  = v ? dv[b] : d0r;
                    d1r  = v ? dv[b + 1] : d1r;
                }

                float spl0 = sp_softplus(d0r), spl1 = sp_softplus(d1r);
                float d0 = gt0 ? (MIN_Dc + spl0) : 1.f;
                float d1 = lt15 ? (MIN_Dc + spl1) : 1.f;

                float rw = __builtin_amdgcn_rcpf(curw);
                float delta = curh * rw;
                float th = (xcv - lw) * rw;
                float omt = 1.f - th;
                float tomt = th * omt;
                float num = curh * (delta * th * th + d0 * tomt);
                float den = delta + (d0 + d1 - 2.f * delta) * tomt;
                float rd = __builtin_amdgcn_rcpf(den);
                float y = chl + num * rd;
                float dnum = delta * delta * (d1 * th * th + 2.f * delta * tomt + d0 * omt * omt);
                // log(dnum) - 2*log(den) == log(dnum * rd * rd): ONE transcendental
                float lad = 0.69314718055994531f * __log2f(dnum * rd * rd);

                y = inside ? y : xr;
                lad = inside ? lad : 0.f;
                xs[srow * 17 + f] = y;
                lad_sum += lad;
            }
        }

        // ---- advance ring over pad frags 211..223 (keeps ring phase across layers)
#pragma unroll
        for (int d = 0; d < FRAGS_PAD - FRAGS_USED; d++) {
            (void)ldfrag();
        }

        wl += (size_t)FRAGS_PAD * FRAG_ELEMS;
    }

    // ---- epilogue: logdet (fi pair sums) + z write
    float v = lad_sum;
    v += __shfl_xor(v, 1);
    if (fi == 0) ldout[(size_t)sbase + srow] = v;

    for (int t = ln; t < SPW * FDIM; t += 64) {
        int s = t / FDIM, c = t % FDIM;
        zout[(size_t)sbase * FDIM + t] = xs[s * 17 + c];
    }
}

extern "C" void kernel_launch(void* const* d_in, const int* in_sizes, int n_in,
                              void* d_out, int out_size, void* d_ws, size_t ws_size,
                              hipStream_t stream) {
    const float* x  = (const float*)d_in[0];
    const float* Wi = (const float*)d_in[1];
    const float* bI = (const float*)d_in[2];
    const float* Wr = (const float*)d_in[3];
    const float* bR = (const float*)d_in[4];
    const float* Wo = (const float*)d_in[5];
    const float* bO = (const float*)d_in[6];

    bf16_t* wfrag = (bf16_t*)d_ws;
    // slack of RING frags (16 KB) after the last layer for tail prefetches
    size_t woff = ((size_t)WFRAG_TOTAL * 2 + (size_t)RING * FRAG_ELEMS * 2 + 255) & ~(size_t)255;
    float* bblob = (float*)((char*)d_ws + woff);
    float* zout  = (float*)d_out;
    float* ldout_final = zout + (size_t)BATCH * FDIM;

    const int totalP = WFRAG_TOTAL + BB_TOTAL;
    preproc_kernel<<<(totalP + 255) / 256, 256, 0, stream>>>(Wi, Wr, Wo, bI, bR, bO, wfrag, bblob);

    flow_kernel<<<BATCH / SPW, 64, 0, stream>>>(x, zout, ldout_final, wfrag, bblob);
}